// Round 4
// baseline (197.884 us; speedup 1.0000x reference)
//
#include <hip/hip_runtime.h>

// TwoStageRegressionLoss: fused BCE + duration-aware focal smooth-L1 mean
// reduction over N = 2048*16384 fp32 elements per array (4 input arrays).
// R1: libm logf -> VALU-bound 77%. R2: hw __log2f -> 101us, VALUBusy 20%.
// R3: cross-iteration SW pipeline FAILED (compiler sank loads; 104.6us).
// R4: (a) 2-position loop body w/ 8 up-front independent float4 loads (MLP
//     the compiler preserves), (b) single kernel: deterministic fixed-point
//     int64 atomic reduction + last-block finalize (kills 2nd launch),
//     (c) BCE in log2 domain (scale by ln2 once at the end).

constexpr int BLOCK = 256;
constexpr int GRID  = 2048;   // 256 CUs x 8 blocks resident
constexpr double SCALE = 16777216.0;        // 2^24 fixed-point
constexpr double LN2D  = 0.6931471805599453;

__device__ __forceinline__ void accum_elem(float pv, float tv, float qv, float sv,
                                           float& accB, float& accR) {
    // --- BCE, log2 domain. clamp(-100) in ln == clamp(-100/ln2) in log2. ---
    constexpr float CLAMP2 = -144.26950408889634f;
    float pc = fminf(fmaxf(pv, 0.0f), 1.0f);
    float tc = fminf(fmaxf(tv, 0.0f), 1.0f);
    float lp  = fmaxf(__log2f(pc),        CLAMP2);  // v_log_f32; log2(0)=-inf -> clamp
    float l1p = fmaxf(__log2f(1.0f - pc), CLAMP2);
    accB -= l1p + tc * (lp - l1p);   // == tc*lp + (1-tc)*l1p; *ln2 at the end
    // --- duration-aware focal smooth-L1 (alpha=0.25 applied at the end) ---
    float d = fabsf(qv - sv);
    float f = fminf(d + d, 1.0f);                     // clip(d/0.5, 0, 1)
    float base = (d < 0.5f) ? (d * d) : (d - 0.25f);  // smooth L1 * delta-scale
    // class weight: round-half-even (jnp.round), clamp [0,3], table {1,4,3,2}
    float r = fminf(fmaxf(__builtin_rintf(sv), 0.0f), 3.0f);
    float w = (r == 0.0f) ? 1.0f : (r == 1.0f) ? 4.0f : (r == 2.0f) ? 3.0f : 2.0f;
    accR += (f * f) * base * w;
}

__device__ __forceinline__ void accum4(const float4& p, const float4& t,
                                       const float4& q, const float4& s,
                                       float& accB0, float& accR0,
                                       float& accB1, float& accR1) {
    accum_elem(p.x, t.x, q.x, s.x, accB0, accR0);
    accum_elem(p.y, t.y, q.y, s.y, accB1, accR1);
    accum_elem(p.z, t.z, q.z, s.z, accB0, accR0);
    accum_elem(p.w, t.w, q.w, s.w, accB1, accR1);
}

__global__ __launch_bounds__(BLOCK) void loss_kernel(
    const float4* __restrict__ bp4, const float4* __restrict__ rp4,
    const float4* __restrict__ bt4, const float4* __restrict__ rt4,
    unsigned long long* __restrict__ ws,   // [0]=sumB q24, [1]=sumR q24, [2]=counter
    float* __restrict__ out, int n4, int n, double invN)
{
    float accB0 = 0.0f, accR0 = 0.0f, accB1 = 0.0f, accR1 = 0.0f;
    const int stride = GRID * BLOCK;
    int i = blockIdx.x * BLOCK + threadIdx.x;
    // 2-position body: all 8 independent float4 loads issue before any math.
    for (; i + stride < n4; i += 2 * stride) {
        float4 p0 = bp4[i],          q0 = rp4[i],          t0 = bt4[i],          s0 = rt4[i];
        float4 p1 = bp4[i + stride], q1 = rp4[i + stride], t1 = bt4[i + stride], s1 = rt4[i + stride];
        accum4(p0, t0, q0, s0, accB0, accR0, accB1, accR1);
        accum4(p1, t1, q1, s1, accB0, accR0, accB1, accR1);
    }
    if (i < n4) {
        float4 p = bp4[i], q = rp4[i], t = bt4[i], s = rt4[i];
        accum4(p, t, q, s, accB0, accR0, accB1, accR1);
    }
    // scalar tail (n not multiple of 4) -- block 0 only
    if (blockIdx.x == 0) {
        const float* bp = (const float*)bp4;
        const float* bt = (const float*)bt4;
        const float* rp = (const float*)rp4;
        const float* rt = (const float*)rt4;
        for (int k = n4 * 4 + threadIdx.x; k < n; k += BLOCK)
            accum_elem(bp[k], bt[k], rp[k], rt[k], accB0, accR0);
    }
    float accB = accB0 + accB1;
    float accR = accR0 + accR1;
    // wave-64 reduce
    #pragma unroll
    for (int off = 32; off > 0; off >>= 1) {
        accB += __shfl_down(accB, off, 64);
        accR += __shfl_down(accR, off, 64);
    }
    __shared__ float sB[BLOCK / 64], sR[BLOCK / 64];
    const int lane = threadIdx.x & 63;
    const int wid  = threadIdx.x >> 6;
    if (lane == 0) { sB[wid] = accB; sR[wid] = accR; }
    __syncthreads();
    if (threadIdx.x == 0) {
        float b = 0.0f, r = 0.0f;
        #pragma unroll
        for (int w = 0; w < BLOCK / 64; ++w) { b += sB[w]; r += sR[w]; }
        // deterministic fixed-point reduce: int64 adds are associative.
        // block sums are non-negative; q24 quantization err ~2^-25/block.
        unsigned long long bq = (unsigned long long)(long long)llrint((double)b * LN2D  * SCALE);
        unsigned long long rq = (unsigned long long)(long long)llrint((double)r * 0.25 * SCALE);
        atomicAdd(&ws[0], bq);
        atomicAdd(&ws[1], rq);
        __threadfence();                       // sums visible before counter bump
        unsigned long long prev = atomicAdd(&ws[2], 1ULL);
        if (prev == (unsigned long long)(GRID - 1)) {   // last block finalizes
            unsigned long long tb = atomicAdd(&ws[0], 0ULL);  // device-scope read
            unsigned long long tr = atomicAdd(&ws[1], 0ULL);
            double bm = (double)(long long)tb / SCALE * invN;
            double rm = (double)(long long)tr / SCALE * invN;
            out[0] = (float)(bm + rm);  // total (BREAK_W = REG_W = 1)
            out[1] = (float)bm;         // break_loss
            out[2] = (float)rm;         // regression_loss
        }
    }
}

extern "C" void kernel_launch(void* const* d_in, const int* in_sizes, int n_in,
                              void* d_out, int out_size, void* d_ws, size_t ws_size,
                              hipStream_t stream) {
    // setup_inputs() order: break_predictions, regression_predictions,
    //                       break_targets, regression_targets  (all fp32)
    const float* bp = (const float*)d_in[0];
    const float* rp = (const float*)d_in[1];
    const float* bt = (const float*)d_in[2];
    const float* rt = (const float*)d_in[3];
    const int n  = in_sizes[0];
    const int n4 = n / 4;
    unsigned long long* ws = (unsigned long long*)d_ws;

    // ws is poisoned 0xAA once and never re-poisoned -> zero it every call.
    // hipMemsetAsync is graph-capture-safe (the harness itself uses it).
    hipMemsetAsync(ws, 0, 3 * sizeof(unsigned long long), stream);
    loss_kernel<<<GRID, BLOCK, 0, stream>>>(
        (const float4*)bp, (const float4*)rp, (const float4*)bt, (const float4*)rt,
        ws, (float*)d_out, n4, n, 1.0 / (double)n);
}

// Round 6
// 102.370 us; speedup vs baseline: 1.9330x; 1.9330x over previous
//
#include <hip/hip_runtime.h>

// TwoStageRegressionLoss: fused BCE + duration-aware focal smooth-L1 mean
// reduction over N = 2048*16384 fp32 elements per array (4 input arrays).
// History: R1 libm logf -> VALU-bound 77%. R2 hw __log2f -> 101us (anchor,
// VALUBusy 20%, HBM 22%, VGPR 16). R3/R4 source-level MLP -> compiler sank
// loads, regressed. R5 inline-asm loads -> GPU fault (compiler doesn't model
// async "=v" dests). Conclusion: per-wave ILP is not the constraint.
// R6: stream specialization - BCE blocks read only (bp,bt), focal blocks
// only (rp,rt). Halves per-wave load-use chain; same total bytes.

constexpr int BLOCK = 256;
constexpr int HGRID = 2048;        // blocks per loss half
constexpr int GRID  = 2 * HGRID;

__device__ __forceinline__ void bce_elem(float pv, float tv, float& acc) {
    // BCE in log2 domain: clamp(-100) in ln == clamp(-100/ln2) in log2.
    // Final scale by ln2 happens once in final_kernel.
    constexpr float CLAMP2 = -144.26950408889634f;
    float pc = fminf(fmaxf(pv, 0.0f), 1.0f);
    float tc = fminf(fmaxf(tv, 0.0f), 1.0f);
    float lp  = fmaxf(__log2f(pc),        CLAMP2);  // v_log_f32; log2(0)=-inf -> clamp
    float l1p = fmaxf(__log2f(1.0f - pc), CLAMP2);
    acc -= l1p + tc * (lp - l1p);   // == tc*lp + (1-tc)*l1p
}

__device__ __forceinline__ void focal_elem(float qv, float sv, float& acc) {
    // duration-aware focal smooth-L1 (alpha=0.25 applied in final_kernel)
    float d = fabsf(qv - sv);
    float f = fminf(d + d, 1.0f);                     // clip(d/0.5, 0, 1)
    float base = (d < 0.5f) ? (d * d) : (d - 0.25f);  // smooth L1, beta=0.5
    // class weight: round-half-even (jnp.round), clamp [0,3], table {1,4,3,2}
    float r = fminf(fmaxf(__builtin_rintf(sv), 0.0f), 3.0f);
    float w = (r == 0.0f) ? 1.0f : (r == 1.0f) ? 4.0f : (r == 2.0f) ? 3.0f : 2.0f;
    acc += (f * f) * base * w;
}

__global__ __launch_bounds__(BLOCK) void partial_kernel(
    const float4* __restrict__ bp4, const float4* __restrict__ rp4,
    const float4* __restrict__ bt4, const float4* __restrict__ rt4,
    float* __restrict__ partials, int n4, int n)
{
    const int stride = HGRID * BLOCK;
    float a0 = 0.0f, a1 = 0.0f;
    const bool isB = (blockIdx.x < HGRID);
    const int  vb  = isB ? blockIdx.x : blockIdx.x - HGRID;

    if (isB) {
        // --- BCE half: streams bp, bt only ---
        for (int i = vb * BLOCK + threadIdx.x; i < n4; i += stride) {
            float4 p = bp4[i];
            float4 t = bt4[i];
            bce_elem(p.x, t.x, a0);
            bce_elem(p.y, t.y, a1);
            bce_elem(p.z, t.z, a0);
            bce_elem(p.w, t.w, a1);
        }
        if (vb == 0) {  // scalar tail
            const float* bp = (const float*)bp4;
            const float* bt = (const float*)bt4;
            for (int k = n4 * 4 + threadIdx.x; k < n; k += BLOCK)
                bce_elem(bp[k], bt[k], a0);
        }
    } else {
        // --- focal half: streams rp, rt only ---
        for (int i = vb * BLOCK + threadIdx.x; i < n4; i += stride) {
            float4 q = rp4[i];
            float4 s = rt4[i];
            focal_elem(q.x, s.x, a0);
            focal_elem(q.y, s.y, a1);
            focal_elem(q.z, s.z, a0);
            focal_elem(q.w, s.w, a1);
        }
        if (vb == 0) {  // scalar tail
            const float* rp = (const float*)rp4;
            const float* rt = (const float*)rt4;
            for (int k = n4 * 4 + threadIdx.x; k < n; k += BLOCK)
                focal_elem(rp[k], rt[k], a0);
        }
    }

    float acc = a0 + a1;
    // wave-64 reduce
    #pragma unroll
    for (int off = 32; off > 0; off >>= 1)
        acc += __shfl_down(acc, off, 64);
    __shared__ float sA[BLOCK / 64];
    const int lane = threadIdx.x & 63;
    const int wid  = threadIdx.x >> 6;
    if (lane == 0) sA[wid] = acc;
    __syncthreads();
    if (threadIdx.x == 0) {
        float v = 0.0f;
        #pragma unroll
        for (int w = 0; w < BLOCK / 64; ++w) v += sA[w];
        partials[blockIdx.x] = v;   // [0..HGRID) = BCE sums, [HGRID..GRID) = focal sums
    }
}

__global__ __launch_bounds__(BLOCK) void final_kernel(
    const float* __restrict__ partials, float* __restrict__ out, double invN)
{
    double accB = 0.0, accR = 0.0;
    for (int i = threadIdx.x; i < HGRID; i += BLOCK) {
        accB += (double)partials[i];
        accR += (double)partials[HGRID + i];
    }
    #pragma unroll
    for (int off = 32; off > 0; off >>= 1) {
        accB += __shfl_down(accB, off, 64);
        accR += __shfl_down(accR, off, 64);
    }
    __shared__ double dB[BLOCK / 64], dR[BLOCK / 64];
    const int lane = threadIdx.x & 63;
    const int wid  = threadIdx.x >> 6;
    if (lane == 0) { dB[wid] = accB; dR[wid] = accR; }
    __syncthreads();
    if (threadIdx.x == 0) {
        double b = 0.0, r = 0.0;
        #pragma unroll
        for (int w = 0; w < BLOCK / 64; ++w) { b += dB[w]; r += dR[w]; }
        const double bm = b * 0.6931471805599453 * invN;  // log2 -> ln
        const double rm = r * 0.25 * invN;                // alpha
        out[0] = (float)(bm + rm);  // total (BREAK_W = REG_W = 1)
        out[1] = (float)bm;         // break_loss
        out[2] = (float)rm;         // regression_loss
    }
}

extern "C" void kernel_launch(void* const* d_in, const int* in_sizes, int n_in,
                              void* d_out, int out_size, void* d_ws, size_t ws_size,
                              hipStream_t stream) {
    // setup_inputs() order: break_predictions, regression_predictions,
    //                       break_targets, regression_targets  (all fp32)
    const float* bp = (const float*)d_in[0];
    const float* rp = (const float*)d_in[1];
    const float* bt = (const float*)d_in[2];
    const float* rt = (const float*)d_in[3];
    const int n  = in_sizes[0];
    const int n4 = n / 4;
    float* partials = (float*)d_ws;   // GRID floats = 16 KB scratch

    partial_kernel<<<GRID, BLOCK, 0, stream>>>(
        (const float4*)bp, (const float4*)rp, (const float4*)bt, (const float4*)rt,
        partials, n4, n);
    final_kernel<<<1, BLOCK, 0, stream>>>(partials, (float*)d_out, 1.0 / (double)n);
}

// Round 7
// 97.452 us; speedup vs baseline: 2.0306x; 1.0505x over previous
//
#include <hip/hip_runtime.h>

// TwoStageRegressionLoss: fused BCE + duration-aware focal smooth-L1 mean
// reduction over N = 2048*16384 fp32 (4 input arrays, 537 MB read).
// History: R1 libm logf VALU-bound 77%. R2 hw __log2f -> 101us anchor.
// R3/R4 VGPR software pipelines -> compiler sank loads (regressed).
// R5 inline-asm "=v" loads -> GPU fault. R6 stream-split -> neutral 102us
// (VGPR 12, occ 78%) => per-wave body is not the limiter; waves drain to
// vmcnt(0) every iteration (burst-then-drain).
// R7: global_load_lds (HW async DMA, compiler-proof) + counted vmcnt(2):
// 3-slot LDS ring per wave, 2 sets of loads permanently in flight, never
// draining until the final iteration. No cross-wave sharing -> no barriers.

constexpr int BLOCK = 256;
constexpr int HGRID = 2048;        // blocks per loss half
constexpr int GRID  = 2 * HGRID;
constexpr int BUFS  = 3;           // LDS ring slots (2 sets in flight + 1 consuming)

typedef float f32x4 __attribute__((ext_vector_type(4)));

// HW async DMA: lane l of the wave writes 16B to lds_base + l*16.
// gptr is PER-LANE; lds base must be wave-uniform (guide §5, m97/m104).
__device__ __forceinline__ void stage16(const float* g, void* l) {
    __builtin_amdgcn_global_load_lds(
        (const __attribute__((address_space(1))) void*)g,
        (__attribute__((address_space(3))) void*)l,
        16, 0, 0);
}

#define WAITV(N) do { \
    asm volatile("s_waitcnt vmcnt(" #N ")" ::: "memory"); \
    __builtin_amdgcn_sched_barrier(0); \
} while (0)

__device__ __forceinline__ void bce_elem(float pv, float tv, float& acc) {
    // BCE in log2 domain: clamp(-100) in ln == clamp(-100/ln2) in log2.
    constexpr float CLAMP2 = -144.26950408889634f;
    float pc = fminf(fmaxf(pv, 0.0f), 1.0f);
    float tc = fminf(fmaxf(tv, 0.0f), 1.0f);
    float lp  = fmaxf(__log2f(pc),        CLAMP2);  // v_log_f32; log2(0)=-inf -> clamp
    float l1p = fmaxf(__log2f(1.0f - pc), CLAMP2);
    acc -= l1p + tc * (lp - l1p);   // == tc*lp + (1-tc)*l1p; *ln2 in final_kernel
}

__device__ __forceinline__ void focal_elem(float qv, float sv, float& acc) {
    // duration-aware focal smooth-L1 (alpha=0.25 applied in final_kernel)
    float d = fabsf(qv - sv);
    float f = fminf(d + d, 1.0f);                     // clip(d/0.5, 0, 1)
    float base = (d < 0.5f) ? (d * d) : (d - 0.25f);  // smooth L1, beta=0.5
    // class weight: round-half-even (jnp.round), clamp [0,3], table {1,4,3,2}
    float r = fminf(fmaxf(__builtin_rintf(sv), 0.0f), 3.0f);
    float w = (r == 0.0f) ? 1.0f : (r == 1.0f) ? 4.0f : (r == 2.0f) ? 3.0f : 2.0f;
    acc += (f * f) * base * w;
}

template <bool IS_BCE>
__device__ __forceinline__ void accum4(const f32x4& p, const f32x4& t,
                                       float& a0, float& a1) {
    if (IS_BCE) {
        bce_elem(p[0], t[0], a0); bce_elem(p[1], t[1], a1);
        bce_elem(p[2], t[2], a0); bce_elem(p[3], t[3], a1);
    } else {
        focal_elem(p[0], t[0], a0); focal_elem(p[1], t[1], a1);
        focal_elem(p[2], t[2], a0); focal_elem(p[3], t[3], a1);
    }
}

template <bool IS_BCE>
__device__ __forceinline__ void run_half(
    const f32x4* __restrict__ P, const f32x4* __restrict__ T,
    f32x4* smem, int vb, int n4, int n, float& a0, float& a1)
{
    const int tid    = (int)threadIdx.x;
    const int wid    = tid >> 6;
    const int stride = HGRID * BLOCK;           // in float4 units
    const int base   = vb * BLOCK + tid;
    const int iters  = n4 / stride;

    if ((n4 % stride) == 0 && iters >= BUFS) {
        // LDS layout: slot s, stream c -> smem[(s*2+c)*BLOCK + tid]
        // wave-uniform stage base: + wid*64 (HW adds lane*16B)
        // prologue: stage sets 0,1 (4 loads in flight)
        #pragma unroll
        for (int d = 0; d < 2; ++d) {
            stage16((const float*)(P + base + (long)d * stride),
                    (void*)(smem + (d * 2 + 0) * BLOCK + wid * 64));
            stage16((const float*)(T + base + (long)d * stride),
                    (void*)(smem + (d * 2 + 1) * BLOCK + wid * 64));
        }
        for (int it = 0; it < iters; ++it) {
            const int slot = it % BUFS;
            if (it < iters - 1) WAITV(2);    // set `it` done; set it+1 stays in flight
            else                WAITV(0);    // final drain
            // stage set it+2 into slot (it+2)%BUFS == (it-1)%BUFS, which was
            // consumed (ds_read completed) at iteration it-1 -> no alias hazard.
            if (it + 2 < iters) {
                const int s2 = (it + 2) % BUFS;
                stage16((const float*)(P + base + (long)(it + 2) * stride),
                        (void*)(smem + (s2 * 2 + 0) * BLOCK + wid * 64));
                stage16((const float*)(T + base + (long)(it + 2) * stride),
                        (void*)(smem + (s2 * 2 + 1) * BLOCK + wid * 64));
            }
            __builtin_amdgcn_sched_barrier(0);
            f32x4 p = smem[(slot * 2 + 0) * BLOCK + tid];   // ds_read_b128
            f32x4 t = smem[(slot * 2 + 1) * BLOCK + tid];
            accum4<IS_BCE>(p, t, a0, a1);
        }
    } else {
        // generic fallback (R6 structure)
        for (int i = base; i < n4; i += stride) {
            f32x4 p = P[i];
            f32x4 t = T[i];
            accum4<IS_BCE>(p, t, a0, a1);
        }
        if (vb == 0) {  // scalar tail
            const float* Pf = (const float*)P;
            const float* Tf = (const float*)T;
            for (int k = n4 * 4 + tid; k < n; k += BLOCK) {
                if (IS_BCE) bce_elem(Pf[k], Tf[k], a0);
                else        focal_elem(Pf[k], Tf[k], a0);
            }
        }
    }
}

__global__ __launch_bounds__(BLOCK) void partial_kernel(
    const f32x4* __restrict__ bp4, const f32x4* __restrict__ rp4,
    const f32x4* __restrict__ bt4, const f32x4* __restrict__ rt4,
    float* __restrict__ partials, int n4, int n)
{
    __shared__ f32x4 smem[BUFS * 2 * BLOCK];   // 24 KB -> 6 blocks/CU
    float a0 = 0.0f, a1 = 0.0f;
    const bool isB = (blockIdx.x < (unsigned)HGRID);
    const int  vb  = isB ? blockIdx.x : blockIdx.x - HGRID;

    if (isB) run_half<true >(bp4, bt4, smem, vb, n4, n, a0, a1);
    else     run_half<false>(rp4, rt4, smem, vb, n4, n, a0, a1);

    float acc = a0 + a1;
    // wave-64 reduce
    #pragma unroll
    for (int off = 32; off > 0; off >>= 1)
        acc += __shfl_down(acc, off, 64);
    __shared__ float sA[BLOCK / 64];
    const int lane = threadIdx.x & 63;
    const int wid  = threadIdx.x >> 6;
    if (lane == 0) sA[wid] = acc;
    __syncthreads();
    if (threadIdx.x == 0) {
        float v = 0.0f;
        #pragma unroll
        for (int w = 0; w < BLOCK / 64; ++w) v += sA[w];
        partials[blockIdx.x] = v;   // [0..HGRID) BCE sums, [HGRID..GRID) focal sums
    }
}

__global__ __launch_bounds__(BLOCK) void final_kernel(
    const float* __restrict__ partials, float* __restrict__ out, double invN)
{
    double accB = 0.0, accR = 0.0;
    for (int i = threadIdx.x; i < HGRID; i += BLOCK) {
        accB += (double)partials[i];
        accR += (double)partials[HGRID + i];
    }
    #pragma unroll
    for (int off = 32; off > 0; off >>= 1) {
        accB += __shfl_down(accB, off, 64);
        accR += __shfl_down(accR, off, 64);
    }
    __shared__ double dB[BLOCK / 64], dR[BLOCK / 64];
    const int lane = threadIdx.x & 63;
    const int wid  = threadIdx.x >> 6;
    if (lane == 0) { dB[wid] = accB; dR[wid] = accR; }
    __syncthreads();
    if (threadIdx.x == 0) {
        double b = 0.0, r = 0.0;
        #pragma unroll
        for (int w = 0; w < BLOCK / 64; ++w) { b += dB[w]; r += dR[w]; }
        const double bm = b * 0.6931471805599453 * invN;  // log2 -> ln
        const double rm = r * 0.25 * invN;                // alpha
        out[0] = (float)(bm + rm);  // total (BREAK_W = REG_W = 1)
        out[1] = (float)bm;         // break_loss
        out[2] = (float)rm;         // regression_loss
    }
}

extern "C" void kernel_launch(void* const* d_in, const int* in_sizes, int n_in,
                              void* d_out, int out_size, void* d_ws, size_t ws_size,
                              hipStream_t stream) {
    // setup_inputs() order: break_predictions, regression_predictions,
    //                       break_targets, regression_targets  (all fp32)
    const float* bp = (const float*)d_in[0];
    const float* rp = (const float*)d_in[1];
    const float* bt = (const float*)d_in[2];
    const float* rt = (const float*)d_in[3];
    const int n  = in_sizes[0];
    const int n4 = n / 4;
    float* partials = (float*)d_ws;   // GRID floats = 16 KB scratch

    partial_kernel<<<GRID, BLOCK, 0, stream>>>(
        (const f32x4*)bp, (const f32x4*)rp, (const f32x4*)bt, (const f32x4*)rt,
        partials, n4, n);
    final_kernel<<<1, BLOCK, 0, stream>>>(partials, (float*)d_out, 1.0 / (double)n);
}